// Round 2
// baseline (475.266 us; speedup 1.0000x reference)
//
#include <hip/hip_runtime.h>
#include <math.h>

#define B 32
#define C 256
#define L 8192
#define H 16

#define RPB  8                    // rows per block in the scale kernel
#define NBLK (B * C / RPB)        // 1024 blocks

typedef float v4f __attribute__((ext_vector_type(4)));

// ---------------------------------------------------------------------------
// Kernel 1: per-(b,c) row mean over L. One 256-thread block per row.
// (Unchanged from the verified Round-0 kernel.)
// ---------------------------------------------------------------------------
__global__ __launch_bounds__(256) void k_mean(const float* __restrict__ x,
                                              float* __restrict__ y) {
    const int row = blockIdx.x;  // b*C + c
    const v4f* xr = (const v4f*)(x + (size_t)row * L);
    float s = 0.f;
#pragma unroll
    for (int i = 0; i < 8; ++i) {
        v4f v = xr[threadIdx.x + i * 256];
        s += (v.x + v.y) + (v.z + v.w);
    }
#pragma unroll
    for (int off = 32; off > 0; off >>= 1)
        s += __shfl_down(s, off, 64);
    __shared__ float ws[4];
    const int lane = threadIdx.x & 63;
    const int wave = threadIdx.x >> 6;
    if (lane == 0) ws[wave] = s;
    __syncthreads();
    if (threadIdx.x == 0) {
        float t = (ws[0] + ws[1]) + (ws[2] + ws[3]);
        y[row] = t * (1.0f / (float)L);
    }
}

// ---------------------------------------------------------------------------
// Kernel 2: fused excite + scale. Each block owns 8 contiguous rows (all in
// one batch b). It recomputes the tiny MLP for batch b redundantly (4K MACs,
// W1/W2 L2-resident), then scales its rows. The kernel boundary after
// k_mean is the global sync — no grid barrier, no deadlock risk.
// ---------------------------------------------------------------------------
__global__ __launch_bounds__(256) void k_mlp_scale(
    const float* __restrict__ x,   // [B, C, L]
    const float* __restrict__ y,   // [B*C] means
    const float* __restrict__ W1,  // [H, C]
    const float* __restrict__ W2,  // [C, H]
    float* __restrict__ out)       // [B, C, L]
{
    const int tid  = threadIdx.x;
    const int row0 = blockIdx.x * RPB;
    const int b    = row0 / C;     // RPB divides C -> one batch per block

    __shared__ float ys[C];
    __shared__ float part[16][H + 1];
    __shared__ float hs[H];
    __shared__ float gs[RPB];

    // ---- excite (redundant per block, identical math to Round-0 k_mlp) ----
    ys[tid] = y[b * C + tid];
    __syncthreads();
    {
        const int j = tid & 15;    // h unit
        const int k = tid >> 4;    // c chunk
        const float* w  = W1 + j * C + k * 16;
        const float* yy = ys + k * 16;
        float s = 0.f;
#pragma unroll
        for (int c = 0; c < 16; ++c) s += yy[c] * w[c];
        part[k][j] = s;
    }
    __syncthreads();
    if (tid < H) {
        float s = 0.f;
#pragma unroll
        for (int k = 0; k < 16; ++k) s += part[k][tid];
        hs[tid] = fmaxf(s, 0.f);
    }
    __syncthreads();
    if (tid < RPB) {
        const int c = (row0 + tid) & (C - 1);
        const float* w2 = W2 + c * H;
        float s = 0.f;
#pragma unroll
        for (int j = 0; j < H; ++j) s += hs[j] * w2[j];
        gs[tid] = 1.0f / (1.0f + __expf(-s));
    }
    __syncthreads();

    // ---- scale my 8 rows; NT stores keep x's L3 lines live ----
    for (int r = 0; r < RPB; ++r) {
        const int row = row0 + r;
        const float gg = gs[r];
        const v4f* xr = (const v4f*)(x + (size_t)row * L);
        v4f* orow = (v4f*)(out + (size_t)row * L);
#pragma unroll
        for (int i = 0; i < 8; ++i) {
            v4f v = xr[tid + i * 256];
            v.x *= gg; v.y *= gg; v.z *= gg; v.w *= gg;
            __builtin_nontemporal_store(v, &orow[tid + i * 256]);
        }
    }
}

extern "C" void kernel_launch(void* const* d_in, const int* in_sizes, int n_in,
                              void* d_out, int out_size, void* d_ws, size_t ws_size,
                              hipStream_t stream) {
    const float* x  = (const float*)d_in[0];   // [B, C, L]
    const float* W1 = (const float*)d_in[1];   // [H, C]
    const float* W2 = (const float*)d_in[2];   // [C, H]
    float* out = (float*)d_out;                // [B, C, L]

    float* y = (float*)d_ws;                   // [B*C] means

    k_mean<<<B * C, 256, 0, stream>>>(x, y);
    k_mlp_scale<<<NBLK, 256, 0, stream>>>(x, y, W1, W2, out);
}

// Round 3
// 469.223 us; speedup vs baseline: 1.0129x; 1.0129x over previous
//
#include <hip/hip_runtime.h>
#include <math.h>

#define B 32
#define C 256
#define L 8192
#define H 16

#define RPB  8                    // rows per block in the scale kernel
#define NBLK (B * C / RPB)        // 1024 blocks

typedef float v4f __attribute__((ext_vector_type(4)));

// ---------------------------------------------------------------------------
// Kernel 1: wave-per-row mean. 4 waves/block -> 4 rows/block, 2048 blocks.
// Each lane accumulates 32 float4 (L/64 lanes/4 = 32), then one 6-step
// shfl reduce. No LDS, no __syncthreads, reduce tail amortized 4x deeper
// than the old block-per-row version.
// ---------------------------------------------------------------------------
__global__ __launch_bounds__(256) void k_mean(const float* __restrict__ x,
                                              float* __restrict__ y) {
    const int wave = threadIdx.x >> 6;
    const int lane = threadIdx.x & 63;
    const int row  = blockIdx.x * 4 + wave;
    const v4f* xr = (const v4f*)(x + (size_t)row * L);
    float s = 0.f;
#pragma unroll
    for (int i = 0; i < 32; ++i) {
        v4f v = xr[lane + i * 64];
        s += (v.x + v.y) + (v.z + v.w);
    }
#pragma unroll
    for (int off = 32; off > 0; off >>= 1)
        s += __shfl_down(s, off, 64);
    if (lane == 0) y[row] = s * (1.0f / (float)L);
}

// ---------------------------------------------------------------------------
// Kernel 2: fused excite + scale (unchanged from the verified Round-2
// kernel). Each block owns 8 contiguous rows of one batch b, recomputes the
// tiny MLP redundantly (4K MACs, W1/W2 L2-resident), then scales its rows.
// Normal loads for x (L3-warm re-read), NT stores for out.
// ---------------------------------------------------------------------------
__global__ __launch_bounds__(256) void k_mlp_scale(
    const float* __restrict__ x,   // [B, C, L]
    const float* __restrict__ y,   // [B*C] means
    const float* __restrict__ W1,  // [H, C]
    const float* __restrict__ W2,  // [C, H]
    float* __restrict__ out)       // [B, C, L]
{
    const int tid  = threadIdx.x;
    const int row0 = blockIdx.x * RPB;
    const int b    = row0 / C;     // RPB divides C -> one batch per block

    __shared__ float ys[C];
    __shared__ float part[16][H + 1];
    __shared__ float hs[H];
    __shared__ float gs[RPB];

    ys[tid] = y[b * C + tid];
    __syncthreads();
    {
        const int j = tid & 15;    // h unit
        const int k = tid >> 4;    // c chunk
        const float* w  = W1 + j * C + k * 16;
        const float* yy = ys + k * 16;
        float s = 0.f;
#pragma unroll
        for (int c = 0; c < 16; ++c) s += yy[c] * w[c];
        part[k][j] = s;
    }
    __syncthreads();
    if (tid < H) {
        float s = 0.f;
#pragma unroll
        for (int k = 0; k < 16; ++k) s += part[k][tid];
        hs[tid] = fmaxf(s, 0.f);
    }
    __syncthreads();
    if (tid < RPB) {
        const int c = (row0 + tid) & (C - 1);
        const float* w2 = W2 + c * H;
        float s = 0.f;
#pragma unroll
        for (int j = 0; j < H; ++j) s += hs[j] * w2[j];
        gs[tid] = 1.0f / (1.0f + __expf(-s));
    }
    __syncthreads();

    for (int r = 0; r < RPB; ++r) {
        const int row = row0 + r;
        const float gg = gs[r];
        const v4f* xr = (const v4f*)(x + (size_t)row * L);
        v4f* orow = (v4f*)(out + (size_t)row * L);
#pragma unroll
        for (int i = 0; i < 8; ++i) {
            v4f v = xr[tid + i * 256];
            v.x *= gg; v.y *= gg; v.z *= gg; v.w *= gg;
            __builtin_nontemporal_store(v, &orow[tid + i * 256]);
        }
    }
}

extern "C" void kernel_launch(void* const* d_in, const int* in_sizes, int n_in,
                              void* d_out, int out_size, void* d_ws, size_t ws_size,
                              hipStream_t stream) {
    const float* x  = (const float*)d_in[0];   // [B, C, L]
    const float* W1 = (const float*)d_in[1];   // [H, C]
    const float* W2 = (const float*)d_in[2];   // [C, H]
    float* out = (float*)d_out;                // [B, C, L]

    float* y = (float*)d_ws;                   // [B*C] means

    k_mean<<<B * C / 4, 256, 0, stream>>>(x, y);
    k_mlp_scale<<<NBLK, 256, 0, stream>>>(x, y, W1, W2, out);
}